// Round 1
// baseline (1616.772 us; speedup 1.0000x reference)
//
#include <hip/hip_runtime.h>
#include <math.h>

#define NN 100000
#define NE 1600000

// ---------------------------------------------------------------------------
// Edge aggregation for layer 1: one wave per edge.
// agg[dst] += x[src]  (128 floats, 2 per lane), degf[dst] += 1.
// ---------------------------------------------------------------------------
__global__ __launch_bounds__(256) void agg1_kernel(
    const float* __restrict__ x, const int* __restrict__ src,
    const int* __restrict__ dst, float* __restrict__ agg,
    float* __restrict__ degf) {
  int gid  = blockIdx.x * 256 + threadIdx.x;
  int e    = gid >> 6;
  int lane = threadIdx.x & 63;
  if (e >= NE) return;
  int s = src[e], d = dst[e];
  float2 v = *(const float2*)(x + (size_t)s * 128 + lane * 2);
  float* p = agg + (size_t)d * 128 + lane * 2;
  atomicAdd(p, v.x);
  atomicAdd(p + 1, v.y);
  if (lane == 0) atomicAdd(degf + d, 1.0f);
}

__global__ __launch_bounds__(256) void rdeg_kernel(
    const float* __restrict__ degf, float* __restrict__ rdeg) {
  int i = blockIdx.x * 256 + threadIdx.x;
  if (i >= NN) return;
  rdeg[i] = 1.0f / fmaxf(degf[i], 1.0f);
}

// ---------------------------------------------------------------------------
// GEMM1: h = relu([x | agg1*rdeg] @ [ws1; wn1] + b1)
// M=NN, K=256 (first 128 from x, last 128 from agg1*rdeg), N=128.
// BM=128, BN=128, BK=16, 256 threads, 8x8 per-thread tile.
// ---------------------------------------------------------------------------
__global__ __launch_bounds__(256) void gemm1_kernel(
    const float* __restrict__ x, const float* __restrict__ hn,
    const float* __restrict__ rdeg, const float* __restrict__ ws1,
    const float* __restrict__ wn1, const float* __restrict__ b1,
    float* __restrict__ h) {
  __shared__ float As[16][132];  // transposed A chunk, padded to 16B-aligned rows
  __shared__ float Bs[16][128];

  int tid = threadIdx.x;
  int tn = tid & 15;   // col group: cols tn*8 .. tn*8+7
  int tm = tid >> 4;   // row group: rows tm*8 .. tm*8+7
  int row0 = blockIdx.x * 128;

  float acc[8][8];
#pragma unroll
  for (int i = 0; i < 8; i++)
#pragma unroll
    for (int j = 0; j < 8; j++) acc[i][j] = 0.0f;

  for (int k0 = 0; k0 < 256; k0 += 16) {
    bool neigh = (k0 >= 128);
    int kk0 = neigh ? (k0 - 128) : k0;
    const float* Asrc = neigh ? hn : x;
    const float* Bsrc = (neigh ? wn1 : ws1) + (size_t)kk0 * 128;

    // load A tile (128 rows x 16 k), transposed into As[k][m]
#pragma unroll
    for (int i = 0; i < 2; i++) {
      int flat = tid * 4 + i * 1024;
      int r = flat >> 4;
      int kk = flat & 15;
      int row = row0 + r;
      if (row >= NN) row = NN - 1;
      float4 v = *(const float4*)(Asrc + (size_t)row * 128 + kk0 + kk);
      if (neigh) {
        float rd = rdeg[row];
        v.x *= rd; v.y *= rd; v.z *= rd; v.w *= rd;
      }
      As[kk][r] = v.x; As[kk + 1][r] = v.y;
      As[kk + 2][r] = v.z; As[kk + 3][r] = v.w;
    }
    // load B tile (16 k x 128 n)
    {
      int r = tid >> 4;
      int n = (tid & 15) * 8;
      const float* p = Bsrc + r * 128 + n;
      *(float4*)&Bs[r][n] = *(const float4*)(p);
      *(float4*)&Bs[r][n + 4] = *(const float4*)(p + 4);
    }
    __syncthreads();

#pragma unroll
    for (int k = 0; k < 16; k++) {
      float a[8], b[8];
      *(float4*)&a[0] = *(const float4*)&As[k][tm * 8];
      *(float4*)&a[4] = *(const float4*)&As[k][tm * 8 + 4];
      *(float4*)&b[0] = *(const float4*)&Bs[k][tn * 8];
      *(float4*)&b[4] = *(const float4*)&Bs[k][tn * 8 + 4];
#pragma unroll
      for (int i = 0; i < 8; i++)
#pragma unroll
        for (int j = 0; j < 8; j++) acc[i][j] += a[i] * b[j];
    }
    __syncthreads();
  }

  // epilogue: + b1, relu, store
#pragma unroll
  for (int i = 0; i < 8; i++) {
    int row = row0 + tm * 8 + i;
    if (row < NN) {
#pragma unroll
      for (int j = 0; j < 8; j += 4) {
        int col = tn * 8 + j;
        float4 v;
        v.x = fmaxf(acc[i][j + 0] + b1[col + 0], 0.0f);
        v.y = fmaxf(acc[i][j + 1] + b1[col + 1], 0.0f);
        v.z = fmaxf(acc[i][j + 2] + b1[col + 2], 0.0f);
        v.w = fmaxf(acc[i][j + 3] + b1[col + 3], 0.0f);
        *(float4*)(h + (size_t)row * 128 + col) = v;
      }
    }
  }
}

// ---------------------------------------------------------------------------
// GEMM2: [oself | h2] = h @ [ws2 | wn2]   (M=NN, K=128, N=32)
// BM=128, BN=32, BK=16, 256 threads, 8x2 per-thread tile.
// cols 0..15 -> oself (h@ws2), cols 16..31 -> h2 (h@wn2).
// ---------------------------------------------------------------------------
__global__ __launch_bounds__(256) void gemm2_kernel(
    const float* __restrict__ h, const float* __restrict__ ws2,
    const float* __restrict__ wn2, float* __restrict__ oself,
    float* __restrict__ h2) {
  __shared__ float As[16][132];
  __shared__ float Bs[16][32];

  int tid = threadIdx.x;
  int tn = tid & 15;   // cols tn*2, tn*2+1
  int tm = tid >> 4;   // rows tm*8 .. +8
  int row0 = blockIdx.x * 128;

  float acc[8][2];
#pragma unroll
  for (int i = 0; i < 8; i++) { acc[i][0] = 0.0f; acc[i][1] = 0.0f; }

  for (int k0 = 0; k0 < 128; k0 += 16) {
    // load A tile
#pragma unroll
    for (int i = 0; i < 2; i++) {
      int flat = tid * 4 + i * 1024;
      int r = flat >> 4;
      int kk = flat & 15;
      int row = row0 + r;
      if (row >= NN) row = NN - 1;
      float4 v = *(const float4*)(h + (size_t)row * 128 + k0 + kk);
      As[kk][r] = v.x; As[kk + 1][r] = v.y;
      As[kk + 2][r] = v.z; As[kk + 3][r] = v.w;
    }
    // load B tile (16 x 32): flat = tid*2
    {
      int flat = tid * 2;
      int r = flat >> 5;
      int c = flat & 31;
      int k = k0 + r;
      float2 v;
      if (c < 16) {
        v = *(const float2*)(ws2 + (size_t)k * 16 + c);
      } else {
        v = *(const float2*)(wn2 + (size_t)k * 16 + (c - 16));
      }
      *(float2*)&Bs[r][c] = v;
    }
    __syncthreads();

#pragma unroll
    for (int k = 0; k < 16; k++) {
      float a[8], b[2];
      *(float4*)&a[0] = *(const float4*)&As[k][tm * 8];
      *(float4*)&a[4] = *(const float4*)&As[k][tm * 8 + 4];
      float2 bv = *(const float2*)&Bs[k][tn * 2];
      b[0] = bv.x; b[1] = bv.y;
#pragma unroll
      for (int i = 0; i < 8; i++) {
        acc[i][0] += a[i] * b[0];
        acc[i][1] += a[i] * b[1];
      }
    }
    __syncthreads();
  }

#pragma unroll
  for (int i = 0; i < 8; i++) {
    int row = row0 + tm * 8 + i;
    if (row < NN) {
      int col = tn * 2;
      float2 v; v.x = acc[i][0]; v.y = acc[i][1];
      if (col < 16) {
        *(float2*)(oself + (size_t)row * 16 + col) = v;
      } else {
        *(float2*)(h2 + (size_t)row * 16 + (col - 16)) = v;
      }
    }
  }
}

// ---------------------------------------------------------------------------
// Edge aggregation for layer 2: 16 lanes per edge (h2 is [N,16]).
// ---------------------------------------------------------------------------
__global__ __launch_bounds__(256) void agg2_kernel(
    const float* __restrict__ h2, const int* __restrict__ src,
    const int* __restrict__ dst, float* __restrict__ agg2) {
  int gid = blockIdx.x * 256 + threadIdx.x;
  int e = gid >> 4;
  int c = threadIdx.x & 15;
  if (e >= NE) return;
  int s = src[e], d = dst[e];
  float v = h2[(size_t)s * 16 + c];
  atomicAdd(agg2 + (size_t)d * 16 + c, v);
}

// ---------------------------------------------------------------------------
// Final: logits = oself + b2 + agg2*rdeg; out = log_softmax(logits). 1 thread/node.
// ---------------------------------------------------------------------------
__global__ __launch_bounds__(256) void final_kernel(
    const float* __restrict__ oself, const float* __restrict__ agg2,
    const float* __restrict__ rdeg, const float* __restrict__ b2,
    float* __restrict__ out) {
  int i = blockIdx.x * 256 + threadIdx.x;
  if (i >= NN) return;
  float rd = rdeg[i];
  float l[16];
  const float4* po = (const float4*)(oself + (size_t)i * 16);
  const float4* pa = (const float4*)(agg2 + (size_t)i * 16);
#pragma unroll
  for (int q = 0; q < 4; q++) {
    float4 o = po[q], a = pa[q];
    l[q * 4 + 0] = o.x + b2[q * 4 + 0] + a.x * rd;
    l[q * 4 + 1] = o.y + b2[q * 4 + 1] + a.y * rd;
    l[q * 4 + 2] = o.z + b2[q * 4 + 2] + a.z * rd;
    l[q * 4 + 3] = o.w + b2[q * 4 + 3] + a.w * rd;
  }
  float m = l[0];
#pragma unroll
  for (int c = 1; c < 16; c++) m = fmaxf(m, l[c]);
  float s = 0.0f;
#pragma unroll
  for (int c = 0; c < 16; c++) s += expf(l[c] - m);
  float ls = logf(s);
  float4* po2 = (float4*)(out + (size_t)i * 16);
#pragma unroll
  for (int q = 0; q < 4; q++) {
    float4 v;
    v.x = l[q * 4 + 0] - m - ls;
    v.y = l[q * 4 + 1] - m - ls;
    v.z = l[q * 4 + 2] - m - ls;
    v.w = l[q * 4 + 3] - m - ls;
    po2[q] = v;
  }
}

// ---------------------------------------------------------------------------
extern "C" void kernel_launch(void* const* d_in, const int* in_sizes, int n_in,
                              void* d_out, int out_size, void* d_ws, size_t ws_size,
                              hipStream_t stream) {
  const float* x   = (const float*)d_in[0];
  const int*   src = (const int*)d_in[1];
  const int*   dst = (const int*)d_in[2];
  const float* ws1 = (const float*)d_in[3];
  const float* wn1 = (const float*)d_in[4];
  const float* b1  = (const float*)d_in[5];
  const float* ws2 = (const float*)d_in[6];
  const float* wn2 = (const float*)d_in[7];
  const float* b2  = (const float*)d_in[8];
  float* out = (float*)d_out;

  // workspace layout (floats); total = 30.6M floats = 122.4 MB
  float* p = (float*)d_ws;
  float* agg1 = p; p += (size_t)NN * 128;
  float* agg2 = p; p += (size_t)NN * 16;
  float* degf = p; p += NN;
  float* rdeg = p; p += NN;
  float* h    = p; p += (size_t)NN * 128;
  float* h2   = p; p += (size_t)NN * 16;
  float* osf  = p; p += (size_t)NN * 16;

  // zero the accumulators (agg1 | agg2 | degf are contiguous at the front)
  hipMemsetAsync(agg1, 0, ((size_t)NN * 128 + (size_t)NN * 16 + NN) * sizeof(float),
                 stream);

  agg1_kernel<<<NE / 4, 256, 0, stream>>>(x, src, dst, agg1, degf);
  rdeg_kernel<<<(NN + 255) / 256, 256, 0, stream>>>(degf, rdeg);
  gemm1_kernel<<<(NN + 127) / 128, 256, 0, stream>>>(x, agg1, rdeg, ws1, wn1, b1, h);
  gemm2_kernel<<<(NN + 127) / 128, 256, 0, stream>>>(h, ws2, wn2, osf, h2);
  agg2_kernel<<<(NE * 16 + 255) / 256, 256, 0, stream>>>(h2, src, dst, agg2);
  final_kernel<<<(NN + 255) / 256, 256, 0, stream>>>(osf, agg2, rdeg, b2, out);
}

// Round 2
// 638.173 us; speedup vs baseline: 2.5334x; 2.5334x over previous
//
#include <hip/hip_runtime.h>
#include <math.h>

#define NN 100000
#define NE 1600000

// ---------------------------------------------------------------------------
// CSR build step 1: in-degree histogram (int atomics, cheap).
// ---------------------------------------------------------------------------
__global__ __launch_bounds__(256) void hist_kernel(
    const int* __restrict__ dst, int* __restrict__ deg) {
  int e = blockIdx.x * 256 + threadIdx.x;
  if (e >= NE) return;
  atomicAdd(&deg[dst[e]], 1);
}

// ---------------------------------------------------------------------------
// CSR build step 2: exclusive prefix sum over deg -> off, cur.
// Single 1024-thread block, Hillis-Steele per 1024-chunk with running carry.
// ---------------------------------------------------------------------------
__global__ __launch_bounds__(1024) void scan_kernel(
    const int* __restrict__ deg, int* __restrict__ off, int* __restrict__ cur) {
  __shared__ int buf[2][1024];
  __shared__ int carry_s;
  int tid = threadIdx.x;
  if (tid == 0) carry_s = 0;
  __syncthreads();
  for (int base = 0; base < NN; base += 1024) {
    int i = base + tid;
    int v = (i < NN) ? deg[i] : 0;
    buf[0][tid] = v;
    __syncthreads();
    int pp = 0;
#pragma unroll
    for (int d = 1; d < 1024; d <<= 1) {
      int val = buf[pp][tid] + ((tid >= d) ? buf[pp][tid - d] : 0);
      buf[pp ^ 1][tid] = val;
      pp ^= 1;
      __syncthreads();
    }
    int incl = buf[pp][tid];
    int carry = carry_s;
    __syncthreads();
    if (i < NN) {
      int e = carry + incl - v;
      off[i] = e;
      cur[i] = e;
    }
    if (tid == 1023) carry_s = carry + incl;
    __syncthreads();
  }
}

// ---------------------------------------------------------------------------
// CSR build step 3: scatter src into perm grouped by dst.
// (order within a node is atomic-race-ordered; sum-order noise only)
// ---------------------------------------------------------------------------
__global__ __launch_bounds__(256) void scatter_kernel(
    const int* __restrict__ src, const int* __restrict__ dst,
    int* __restrict__ cur, int* __restrict__ perm) {
  int e = blockIdx.x * 256 + threadIdx.x;
  if (e >= NE) return;
  int p = atomicAdd(&cur[dst[e]], 1);
  perm[p] = src[e];
}

// ---------------------------------------------------------------------------
// Layer-1 mean aggregation, gather form: one wave per node, 2 floats/lane.
// Writes mean directly (agg/deg) -> no rdeg needed downstream.
// ---------------------------------------------------------------------------
__global__ __launch_bounds__(256) void mean1_kernel(
    const float* __restrict__ x, const int* __restrict__ off,
    const int* __restrict__ deg, const int* __restrict__ perm,
    float* __restrict__ mean1) {
  int node = blockIdx.x * 4 + (threadIdx.x >> 6);
  int lane = threadIdx.x & 63;
  if (node >= NN) return;
  int o = off[node], dg = deg[node];
  float accx = 0.f, accy = 0.f;
  int j = 0;
  for (; j + 2 <= dg; j += 2) {   // unroll-2 for load ILP
    int s0 = perm[o + j], s1 = perm[o + j + 1];
    float2 v0 = *(const float2*)(x + (size_t)s0 * 128 + lane * 2);
    float2 v1 = *(const float2*)(x + (size_t)s1 * 128 + lane * 2);
    accx += v0.x + v1.x;
    accy += v0.y + v1.y;
  }
  if (j < dg) {
    int s0 = perm[o + j];
    float2 v0 = *(const float2*)(x + (size_t)s0 * 128 + lane * 2);
    accx += v0.x;
    accy += v0.y;
  }
  float rd = 1.0f / fmaxf((float)dg, 1.0f);
  float2 r;
  r.x = accx * rd;
  r.y = accy * rd;
  *(float2*)(mean1 + (size_t)node * 128 + lane * 2) = r;
}

// ---------------------------------------------------------------------------
// GEMM1: h = relu([x | mean1] @ [ws1; wn1] + b1)
// M=NN, K=256, N=128. BM=128, BN=128, BK=16, 256 threads, 8x8/thread.
// NOTE: h may alias mean1 — each block reads only its own 128 rows of mean1
// during the k-loop and writes the same rows only in the epilogue.
// ---------------------------------------------------------------------------
__global__ __launch_bounds__(256) void gemm1_kernel(
    const float* __restrict__ x, const float* __restrict__ hn,
    const float* __restrict__ ws1, const float* __restrict__ wn1,
    const float* __restrict__ b1, float* __restrict__ h) {
  __shared__ float As[16][132];
  __shared__ float Bs[16][128];

  int tid = threadIdx.x;
  int tn = tid & 15;
  int tm = tid >> 4;
  int row0 = blockIdx.x * 128;

  float acc[8][8];
#pragma unroll
  for (int i = 0; i < 8; i++)
#pragma unroll
    for (int j = 0; j < 8; j++) acc[i][j] = 0.0f;

  for (int k0 = 0; k0 < 256; k0 += 16) {
    bool neigh = (k0 >= 128);
    int kk0 = neigh ? (k0 - 128) : k0;
    const float* Asrc = neigh ? hn : x;
    const float* Bsrc = (neigh ? wn1 : ws1) + (size_t)kk0 * 128;

#pragma unroll
    for (int i = 0; i < 2; i++) {
      int flat = tid * 4 + i * 1024;
      int r = flat >> 4;
      int kk = flat & 15;
      int row = row0 + r;
      if (row >= NN) row = NN - 1;
      float4 v = *(const float4*)(Asrc + (size_t)row * 128 + kk0 + kk);
      As[kk][r] = v.x; As[kk + 1][r] = v.y;
      As[kk + 2][r] = v.z; As[kk + 3][r] = v.w;
    }
    {
      int r = tid >> 4;
      int n = (tid & 15) * 8;
      const float* p = Bsrc + r * 128 + n;
      *(float4*)&Bs[r][n] = *(const float4*)(p);
      *(float4*)&Bs[r][n + 4] = *(const float4*)(p + 4);
    }
    __syncthreads();

#pragma unroll
    for (int k = 0; k < 16; k++) {
      float a[8], b[8];
      *(float4*)&a[0] = *(const float4*)&As[k][tm * 8];
      *(float4*)&a[4] = *(const float4*)&As[k][tm * 8 + 4];
      *(float4*)&b[0] = *(const float4*)&Bs[k][tn * 8];
      *(float4*)&b[4] = *(const float4*)&Bs[k][tn * 8 + 4];
#pragma unroll
      for (int i = 0; i < 8; i++)
#pragma unroll
        for (int j = 0; j < 8; j++) acc[i][j] += a[i] * b[j];
    }
    __syncthreads();
  }

#pragma unroll
  for (int i = 0; i < 8; i++) {
    int row = row0 + tm * 8 + i;
    if (row < NN) {
#pragma unroll
      for (int j = 0; j < 8; j += 4) {
        int col = tn * 8 + j;
        float4 v;
        v.x = fmaxf(acc[i][j + 0] + b1[col + 0], 0.0f);
        v.y = fmaxf(acc[i][j + 1] + b1[col + 1], 0.0f);
        v.z = fmaxf(acc[i][j + 2] + b1[col + 2], 0.0f);
        v.w = fmaxf(acc[i][j + 3] + b1[col + 3], 0.0f);
        *(float4*)(h + (size_t)row * 128 + col) = v;
      }
    }
  }
}

// ---------------------------------------------------------------------------
// GEMM2: [oself | h2] = h @ [ws2 | wn2]   (M=NN, K=128, N=32)
// ---------------------------------------------------------------------------
__global__ __launch_bounds__(256) void gemm2_kernel(
    const float* __restrict__ h, const float* __restrict__ ws2,
    const float* __restrict__ wn2, float* __restrict__ oself,
    float* __restrict__ h2) {
  __shared__ float As[16][132];
  __shared__ float Bs[16][32];

  int tid = threadIdx.x;
  int tn = tid & 15;
  int tm = tid >> 4;
  int row0 = blockIdx.x * 128;

  float acc[8][2];
#pragma unroll
  for (int i = 0; i < 8; i++) { acc[i][0] = 0.0f; acc[i][1] = 0.0f; }

  for (int k0 = 0; k0 < 128; k0 += 16) {
#pragma unroll
    for (int i = 0; i < 2; i++) {
      int flat = tid * 4 + i * 1024;
      int r = flat >> 4;
      int kk = flat & 15;
      int row = row0 + r;
      if (row >= NN) row = NN - 1;
      float4 v = *(const float4*)(h + (size_t)row * 128 + k0 + kk);
      As[kk][r] = v.x; As[kk + 1][r] = v.y;
      As[kk + 2][r] = v.z; As[kk + 3][r] = v.w;
    }
    {
      int flat = tid * 2;
      int r = flat >> 5;
      int c = flat & 31;
      int k = k0 + r;
      float2 v;
      if (c < 16) {
        v = *(const float2*)(ws2 + (size_t)k * 16 + c);
      } else {
        v = *(const float2*)(wn2 + (size_t)k * 16 + (c - 16));
      }
      *(float2*)&Bs[r][c] = v;
    }
    __syncthreads();

#pragma unroll
    for (int k = 0; k < 16; k++) {
      float a[8];
      *(float4*)&a[0] = *(const float4*)&As[k][tm * 8];
      *(float4*)&a[4] = *(const float4*)&As[k][tm * 8 + 4];
      float2 bv = *(const float2*)&Bs[k][tn * 2];
#pragma unroll
      for (int i = 0; i < 8; i++) {
        acc[i][0] += a[i] * bv.x;
        acc[i][1] += a[i] * bv.y;
      }
    }
    __syncthreads();
  }

#pragma unroll
  for (int i = 0; i < 8; i++) {
    int row = row0 + tm * 8 + i;
    if (row < NN) {
      int col = tn * 2;
      float2 v; v.x = acc[i][0]; v.y = acc[i][1];
      if (col < 16) {
        *(float2*)(oself + (size_t)row * 16 + col) = v;
      } else {
        *(float2*)(h2 + (size_t)row * 16 + (col - 16)) = v;
      }
    }
  }
}

// ---------------------------------------------------------------------------
// Layer-2 mean aggregation, gather form: one wave per node,
// 4 edges x 16 cols per iteration, shfl_xor reduce across edge groups.
// ---------------------------------------------------------------------------
__global__ __launch_bounds__(256) void mean2_kernel(
    const float* __restrict__ h2, const int* __restrict__ off,
    const int* __restrict__ deg, const int* __restrict__ perm,
    float* __restrict__ mean2) {
  int node = blockIdx.x * 4 + (threadIdx.x >> 6);
  int lane = threadIdx.x & 63;
  if (node >= NN) return;
  int o = off[node], dg = deg[node];
  int sub = lane >> 4;   // which edge within group of 4
  int c = lane & 15;     // feature column
  float acc = 0.f;
  for (int j = sub; j < dg; j += 4) {
    int s = perm[o + j];
    acc += h2[(size_t)s * 16 + c];
  }
  acc += __shfl_xor(acc, 16);
  acc += __shfl_xor(acc, 32);
  if (sub == 0) {
    float rd = 1.0f / fmaxf((float)dg, 1.0f);
    mean2[(size_t)node * 16 + c] = acc * rd;
  }
}

// ---------------------------------------------------------------------------
// Final: logits = oself + b2 + mean2; out = log_softmax(logits).
// ---------------------------------------------------------------------------
__global__ __launch_bounds__(256) void final_kernel(
    const float* __restrict__ oself, const float* __restrict__ mean2,
    const float* __restrict__ b2, float* __restrict__ out) {
  int i = blockIdx.x * 256 + threadIdx.x;
  if (i >= NN) return;
  float l[16];
  const float4* po = (const float4*)(oself + (size_t)i * 16);
  const float4* pa = (const float4*)(mean2 + (size_t)i * 16);
#pragma unroll
  for (int q = 0; q < 4; q++) {
    float4 o = po[q], a = pa[q];
    l[q * 4 + 0] = o.x + b2[q * 4 + 0] + a.x;
    l[q * 4 + 1] = o.y + b2[q * 4 + 1] + a.y;
    l[q * 4 + 2] = o.z + b2[q * 4 + 2] + a.z;
    l[q * 4 + 3] = o.w + b2[q * 4 + 3] + a.w;
  }
  float m = l[0];
#pragma unroll
  for (int c = 1; c < 16; c++) m = fmaxf(m, l[c]);
  float s = 0.0f;
#pragma unroll
  for (int c = 0; c < 16; c++) s += expf(l[c] - m);
  float ls = logf(s);
  float4* po2 = (float4*)(out + (size_t)i * 16);
#pragma unroll
  for (int q = 0; q < 4; q++) {
    float4 v;
    v.x = l[q * 4 + 0] - m - ls;
    v.y = l[q * 4 + 1] - m - ls;
    v.z = l[q * 4 + 2] - m - ls;
    v.w = l[q * 4 + 3] - m - ls;
    po2[q] = v;
  }
}

// ---------------------------------------------------------------------------
extern "C" void kernel_launch(void* const* d_in, const int* in_sizes, int n_in,
                              void* d_out, int out_size, void* d_ws, size_t ws_size,
                              hipStream_t stream) {
  const float* x   = (const float*)d_in[0];
  const int*   src = (const int*)d_in[1];
  const int*   dst = (const int*)d_in[2];
  const float* ws1 = (const float*)d_in[3];
  const float* wn1 = (const float*)d_in[4];
  const float* b1  = (const float*)d_in[5];
  const float* ws2 = (const float*)d_in[6];
  const float* wn2 = (const float*)d_in[7];
  const float* b2  = (const float*)d_in[8];
  float* out = (float*)d_out;

  // workspace layout: ints first, then float buffers. ~78 MB total.
  char* p = (char*)d_ws;
  int* deg  = (int*)p;  p += (size_t)NN * 4;
  int* off  = (int*)p;  p += (size_t)NN * 4;
  int* cur  = (int*)p;  p += (size_t)NN * 4;
  int* perm = (int*)p;  p += (size_t)NE * 4;
  float* mean1 = (float*)p; p += (size_t)NN * 128 * 4;
  float* h     = mean1;  // alias: gemm1 reads its own rows before writing them
  float* h2    = (float*)p; p += (size_t)NN * 16 * 4;
  float* osf   = (float*)p; p += (size_t)NN * 16 * 4;
  float* mean2 = (float*)p; p += (size_t)NN * 16 * 4;

  hipMemsetAsync(deg, 0, (size_t)NN * 4, stream);

  hist_kernel<<<(NE + 255) / 256, 256, 0, stream>>>(dst, deg);
  scan_kernel<<<1, 1024, 0, stream>>>(deg, off, cur);
  scatter_kernel<<<(NE + 255) / 256, 256, 0, stream>>>(src, dst, cur, perm);
  mean1_kernel<<<(NN + 3) / 4, 256, 0, stream>>>(x, off, deg, perm, mean1);
  gemm1_kernel<<<(NN + 127) / 128, 256, 0, stream>>>(x, mean1, ws1, wn1, b1, h);
  gemm2_kernel<<<(NN + 127) / 128, 256, 0, stream>>>(h, ws2, wn2, osf, h2);
  mean2_kernel<<<(NN + 3) / 4, 256, 0, stream>>>(h2, off, deg, perm, mean2);
  final_kernel<<<(NN + 255) / 256, 256, 0, stream>>>(osf, mean2, b2, out);
}

// Round 3
// 504.739 us; speedup vs baseline: 3.2032x; 1.2644x over previous
//
#include <hip/hip_runtime.h>
#include <math.h>

#define NN 100000
#define NE 1600000
#define NB ((NN + 1023) / 1024)   // 98 scan blocks

// ---------------------------------------------------------------------------
// CSR build step 1: in-degree histogram (int atomics, cheap).
// ---------------------------------------------------------------------------
__global__ __launch_bounds__(256) void hist_kernel(
    const int* __restrict__ dst, int* __restrict__ deg) {
  int e = blockIdx.x * 256 + threadIdx.x;
  if (e >= NE) return;
  atomicAdd(&deg[dst[e]], 1);
}

// ---------------------------------------------------------------------------
// CSR build step 2a: per-block sums of deg (1024 elements per block).
// ---------------------------------------------------------------------------
__global__ __launch_bounds__(1024) void bsum_kernel(
    const int* __restrict__ deg, int* __restrict__ bsum) {
  __shared__ int sdata[1024];
  int i = blockIdx.x * 1024 + threadIdx.x;
  sdata[threadIdx.x] = (i < NN) ? deg[i] : 0;
  __syncthreads();
#pragma unroll
  for (int s = 512; s > 0; s >>= 1) {
    if (threadIdx.x < s) sdata[threadIdx.x] += sdata[threadIdx.x + s];
    __syncthreads();
  }
  if (threadIdx.x == 0) bsum[blockIdx.x] = sdata[0];
}

// ---------------------------------------------------------------------------
// CSR build step 2b: exclusive scan of the 98 block sums (single tiny block).
// ---------------------------------------------------------------------------
__global__ __launch_bounds__(128) void bscan_kernel(int* __restrict__ bsum) {
  __shared__ int buf[2][128];
  int tid = threadIdx.x;
  int v = (tid < NB) ? bsum[tid] : 0;
  buf[0][tid] = v;
  __syncthreads();
  int pp = 0;
#pragma unroll
  for (int d = 1; d < 128; d <<= 1) {
    buf[pp ^ 1][tid] = buf[pp][tid] + ((tid >= d) ? buf[pp][tid - d] : 0);
    pp ^= 1;
    __syncthreads();
  }
  if (tid < NB) bsum[tid] = buf[pp][tid] - v;  // exclusive
}

// ---------------------------------------------------------------------------
// CSR build step 2c: local exclusive scan + block offset -> off, cur.
// ---------------------------------------------------------------------------
__global__ __launch_bounds__(1024) void scan_apply_kernel(
    const int* __restrict__ deg, const int* __restrict__ bsum,
    int* __restrict__ off, int* __restrict__ cur) {
  __shared__ int buf[2][1024];
  int tid = threadIdx.x;
  int i = blockIdx.x * 1024 + tid;
  int v = (i < NN) ? deg[i] : 0;
  buf[0][tid] = v;
  __syncthreads();
  int pp = 0;
#pragma unroll
  for (int d = 1; d < 1024; d <<= 1) {
    buf[pp ^ 1][tid] = buf[pp][tid] + ((tid >= d) ? buf[pp][tid - d] : 0);
    pp ^= 1;
    __syncthreads();
  }
  if (i < NN) {
    int e = bsum[blockIdx.x] + buf[pp][tid] - v;
    off[i] = e;
    cur[i] = e;
  }
}

// ---------------------------------------------------------------------------
// CSR build step 3: scatter src into perm grouped by dst.
// ---------------------------------------------------------------------------
__global__ __launch_bounds__(256) void scatter_kernel(
    const int* __restrict__ src, const int* __restrict__ dst,
    int* __restrict__ cur, int* __restrict__ perm) {
  int e = blockIdx.x * 256 + threadIdx.x;
  if (e >= NE) return;
  int p = atomicAdd(&cur[dst[e]], 1);
  perm[p] = src[e];
}

// ---------------------------------------------------------------------------
// Layer-1 mean aggregation, gather form: one wave per node, 2 floats/lane.
// ---------------------------------------------------------------------------
__global__ __launch_bounds__(256) void mean1_kernel(
    const float* __restrict__ x, const int* __restrict__ off,
    const int* __restrict__ deg, const int* __restrict__ perm,
    float* __restrict__ mean1) {
  int node = blockIdx.x * 4 + (threadIdx.x >> 6);
  int lane = threadIdx.x & 63;
  if (node >= NN) return;
  int o = off[node], dg = deg[node];
  float accx = 0.f, accy = 0.f;
  int j = 0;
  for (; j + 2 <= dg; j += 2) {
    int s0 = perm[o + j], s1 = perm[o + j + 1];
    float2 v0 = *(const float2*)(x + (size_t)s0 * 128 + lane * 2);
    float2 v1 = *(const float2*)(x + (size_t)s1 * 128 + lane * 2);
    accx += v0.x + v1.x;
    accy += v0.y + v1.y;
  }
  if (j < dg) {
    int s0 = perm[o + j];
    float2 v0 = *(const float2*)(x + (size_t)s0 * 128 + lane * 2);
    accx += v0.x;
    accy += v0.y;
  }
  float rd = 1.0f / fmaxf((float)dg, 1.0f);
  float2 r;
  r.x = accx * rd;
  r.y = accy * rd;
  *(float2*)(mean1 + (size_t)node * 128 + lane * 2) = r;
}

// ---------------------------------------------------------------------------
// GEMM1: h = relu([x | mean1] @ [ws1; wn1] + b1)
// M=NN, K=256, N=128. BM=128, BN=128, BK=16, 256 threads, 8x8/thread.
// NOTE: h aliases mean1 — each block reads only its own 128 rows of mean1
// during the k-loop and writes the same rows only in the epilogue.
// ---------------------------------------------------------------------------
__global__ __launch_bounds__(256) void gemm1_kernel(
    const float* __restrict__ x, const float* __restrict__ hn,
    const float* __restrict__ ws1, const float* __restrict__ wn1,
    const float* __restrict__ b1, float* __restrict__ h) {
  __shared__ float As[16][132];
  __shared__ float Bs[16][128];

  int tid = threadIdx.x;
  int tn = tid & 15;
  int tm = tid >> 4;
  int row0 = blockIdx.x * 128;

  float acc[8][8];
#pragma unroll
  for (int i = 0; i < 8; i++)
#pragma unroll
    for (int j = 0; j < 8; j++) acc[i][j] = 0.0f;

  for (int k0 = 0; k0 < 256; k0 += 16) {
    bool neigh = (k0 >= 128);
    int kk0 = neigh ? (k0 - 128) : k0;
    const float* Asrc = neigh ? hn : x;
    const float* Bsrc = (neigh ? wn1 : ws1) + (size_t)kk0 * 128;

#pragma unroll
    for (int i = 0; i < 2; i++) {
      int flat = tid * 4 + i * 1024;
      int r = flat >> 4;
      int kk = flat & 15;
      int row = row0 + r;
      if (row >= NN) row = NN - 1;
      float4 v = *(const float4*)(Asrc + (size_t)row * 128 + kk0 + kk);
      As[kk][r] = v.x; As[kk + 1][r] = v.y;
      As[kk + 2][r] = v.z; As[kk + 3][r] = v.w;
    }
    {
      int r = tid >> 4;
      int n = (tid & 15) * 8;
      const float* p = Bsrc + r * 128 + n;
      *(float4*)&Bs[r][n] = *(const float4*)(p);
      *(float4*)&Bs[r][n + 4] = *(const float4*)(p + 4);
    }
    __syncthreads();

#pragma unroll
    for (int k = 0; k < 16; k++) {
      float a[8], b[8];
      *(float4*)&a[0] = *(const float4*)&As[k][tm * 8];
      *(float4*)&a[4] = *(const float4*)&As[k][tm * 8 + 4];
      *(float4*)&b[0] = *(const float4*)&Bs[k][tn * 8];
      *(float4*)&b[4] = *(const float4*)&Bs[k][tn * 8 + 4];
#pragma unroll
      for (int i = 0; i < 8; i++)
#pragma unroll
        for (int j = 0; j < 8; j++) acc[i][j] += a[i] * b[j];
    }
    __syncthreads();
  }

#pragma unroll
  for (int i = 0; i < 8; i++) {
    int row = row0 + tm * 8 + i;
    if (row < NN) {
#pragma unroll
      for (int j = 0; j < 8; j += 4) {
        int col = tn * 8 + j;
        float4 v;
        v.x = fmaxf(acc[i][j + 0] + b1[col + 0], 0.0f);
        v.y = fmaxf(acc[i][j + 1] + b1[col + 1], 0.0f);
        v.z = fmaxf(acc[i][j + 2] + b1[col + 2], 0.0f);
        v.w = fmaxf(acc[i][j + 3] + b1[col + 3], 0.0f);
        *(float4*)(h + (size_t)row * 128 + col) = v;
      }
    }
  }
}

// ---------------------------------------------------------------------------
// GEMM2: [oself | h2] = h @ [ws2 | wn2]   (M=NN, K=128, N=32)
// ---------------------------------------------------------------------------
__global__ __launch_bounds__(256) void gemm2_kernel(
    const float* __restrict__ h, const float* __restrict__ ws2,
    const float* __restrict__ wn2, float* __restrict__ oself,
    float* __restrict__ h2) {
  __shared__ float As[16][132];
  __shared__ float Bs[16][32];

  int tid = threadIdx.x;
  int tn = tid & 15;
  int tm = tid >> 4;
  int row0 = blockIdx.x * 128;

  float acc[8][2];
#pragma unroll
  for (int i = 0; i < 8; i++) { acc[i][0] = 0.0f; acc[i][1] = 0.0f; }

  for (int k0 = 0; k0 < 128; k0 += 16) {
#pragma unroll
    for (int i = 0; i < 2; i++) {
      int flat = tid * 4 + i * 1024;
      int r = flat >> 4;
      int kk = flat & 15;
      int row = row0 + r;
      if (row >= NN) row = NN - 1;
      float4 v = *(const float4*)(h + (size_t)row * 128 + k0 + kk);
      As[kk][r] = v.x; As[kk + 1][r] = v.y;
      As[kk + 2][r] = v.z; As[kk + 3][r] = v.w;
    }
    {
      int flat = tid * 2;
      int r = flat >> 5;
      int c = flat & 31;
      int k = k0 + r;
      float2 v;
      if (c < 16) {
        v = *(const float2*)(ws2 + (size_t)k * 16 + c);
      } else {
        v = *(const float2*)(wn2 + (size_t)k * 16 + (c - 16));
      }
      *(float2*)&Bs[r][c] = v;
    }
    __syncthreads();

#pragma unroll
    for (int k = 0; k < 16; k++) {
      float a[8];
      *(float4*)&a[0] = *(const float4*)&As[k][tm * 8];
      *(float4*)&a[4] = *(const float4*)&As[k][tm * 8 + 4];
      float2 bv = *(const float2*)&Bs[k][tn * 2];
#pragma unroll
      for (int i = 0; i < 8; i++) {
        acc[i][0] += a[i] * bv.x;
        acc[i][1] += a[i] * bv.y;
      }
    }
    __syncthreads();
  }

#pragma unroll
  for (int i = 0; i < 8; i++) {
    int row = row0 + tm * 8 + i;
    if (row < NN) {
      int col = tn * 2;
      float2 v; v.x = acc[i][0]; v.y = acc[i][1];
      if (col < 16) {
        *(float2*)(oself + (size_t)row * 16 + col) = v;
      } else {
        *(float2*)(h2 + (size_t)row * 16 + (col - 16)) = v;
      }
    }
  }
}

// ---------------------------------------------------------------------------
// Layer-2 mean aggregation, gather form: one wave per node,
// 4 edges x 16 cols per iteration, shfl_xor reduce across edge groups.
// ---------------------------------------------------------------------------
__global__ __launch_bounds__(256) void mean2_kernel(
    const float* __restrict__ h2, const int* __restrict__ off,
    const int* __restrict__ deg, const int* __restrict__ perm,
    float* __restrict__ mean2) {
  int node = blockIdx.x * 4 + (threadIdx.x >> 6);
  int lane = threadIdx.x & 63;
  if (node >= NN) return;
  int o = off[node], dg = deg[node];
  int sub = lane >> 4;
  int c = lane & 15;
  float acc = 0.f;
  for (int j = sub; j < dg; j += 4) {
    int s = perm[o + j];
    acc += h2[(size_t)s * 16 + c];
  }
  acc += __shfl_xor(acc, 16);
  acc += __shfl_xor(acc, 32);
  if (sub == 0) {
    float rd = 1.0f / fmaxf((float)dg, 1.0f);
    mean2[(size_t)node * 16 + c] = acc * rd;
  }
}

// ---------------------------------------------------------------------------
// Final: logits = oself + b2 + mean2; out = log_softmax(logits).
// ---------------------------------------------------------------------------
__global__ __launch_bounds__(256) void final_kernel(
    const float* __restrict__ oself, const float* __restrict__ mean2,
    const float* __restrict__ b2, float* __restrict__ out) {
  int i = blockIdx.x * 256 + threadIdx.x;
  if (i >= NN) return;
  float l[16];
  const float4* po = (const float4*)(oself + (size_t)i * 16);
  const float4* pa = (const float4*)(mean2 + (size_t)i * 16);
#pragma unroll
  for (int q = 0; q < 4; q++) {
    float4 o = po[q], a = pa[q];
    l[q * 4 + 0] = o.x + b2[q * 4 + 0] + a.x;
    l[q * 4 + 1] = o.y + b2[q * 4 + 1] + a.y;
    l[q * 4 + 2] = o.z + b2[q * 4 + 2] + a.z;
    l[q * 4 + 3] = o.w + b2[q * 4 + 3] + a.w;
  }
  float m = l[0];
#pragma unroll
  for (int c = 1; c < 16; c++) m = fmaxf(m, l[c]);
  float s = 0.0f;
#pragma unroll
  for (int c = 0; c < 16; c++) s += expf(l[c] - m);
  float ls = logf(s);
  float4* po2 = (float4*)(out + (size_t)i * 16);
#pragma unroll
  for (int q = 0; q < 4; q++) {
    float4 v;
    v.x = l[q * 4 + 0] - m - ls;
    v.y = l[q * 4 + 1] - m - ls;
    v.z = l[q * 4 + 2] - m - ls;
    v.w = l[q * 4 + 3] - m - ls;
    po2[q] = v;
  }
}

// ---------------------------------------------------------------------------
extern "C" void kernel_launch(void* const* d_in, const int* in_sizes, int n_in,
                              void* d_out, int out_size, void* d_ws, size_t ws_size,
                              hipStream_t stream) {
  const float* x   = (const float*)d_in[0];
  const int*   src = (const int*)d_in[1];
  const int*   dst = (const int*)d_in[2];
  const float* ws1 = (const float*)d_in[3];
  const float* wn1 = (const float*)d_in[4];
  const float* b1  = (const float*)d_in[5];
  const float* ws2 = (const float*)d_in[6];
  const float* wn2 = (const float*)d_in[7];
  const float* b2  = (const float*)d_in[8];
  float* out = (float*)d_out;

  // workspace layout: ints first, then float buffers.
  char* p = (char*)d_ws;
  int* deg  = (int*)p;  p += (size_t)NN * 4;
  int* off  = (int*)p;  p += (size_t)NN * 4;
  int* cur  = (int*)p;  p += (size_t)NN * 4;
  int* bsum = (int*)p;  p += (size_t)((NB + 31) & ~31) * 4;
  int* perm = (int*)p;  p += (size_t)NE * 4;
  float* mean1 = (float*)p; p += (size_t)NN * 128 * 4;
  float* h     = mean1;  // alias: gemm1 reads its own rows before writing them
  float* h2    = (float*)p; p += (size_t)NN * 16 * 4;
  float* osf   = (float*)p; p += (size_t)NN * 16 * 4;
  float* mean2 = (float*)p; p += (size_t)NN * 16 * 4;

  hipMemsetAsync(deg, 0, (size_t)NN * 4, stream);

  hist_kernel<<<(NE + 255) / 256, 256, 0, stream>>>(dst, deg);
  bsum_kernel<<<NB, 1024, 0, stream>>>(deg, bsum);
  bscan_kernel<<<1, 128, 0, stream>>>(bsum);
  scan_apply_kernel<<<NB, 1024, 0, stream>>>(deg, bsum, off, cur);
  scatter_kernel<<<(NE + 255) / 256, 256, 0, stream>>>(src, dst, cur, perm);
  mean1_kernel<<<(NN + 3) / 4, 256, 0, stream>>>(x, off, deg, perm, mean1);
  gemm1_kernel<<<(NN + 127) / 128, 256, 0, stream>>>(x, mean1, ws1, wn1, b1, h);
  gemm2_kernel<<<(NN + 127) / 128, 256, 0, stream>>>(h, ws2, wn2, osf, h2);
  mean2_kernel<<<(NN + 3) / 4, 256, 0, stream>>>(h2, off, deg, perm, mean2);
  final_kernel<<<(NN + 255) / 256, 256, 0, stream>>>(osf, mean2, b2, out);
}